// Round 10
// baseline (167.381 us; speedup 1.0000x reference)
//
#include <hip/hip_runtime.h>

#define N_NODES 65536
#define N_EDGES 1048576
#define DIM 64
#define M_POOL (N_NODES / DIM)  // 1024
#define NCOARSE 256             // coarse buckets (col>>8), 256 nodes each
#define NCHUNK 1024             // edge chunks of 1024 edges
#define SEGCAP 5120             // max edges per coarse bucket (mean 4096, +16 sigma)

typedef unsigned int u32;
typedef unsigned short u16;

__device__ __forceinline__ float bf2f(u32 hi16) {
    return __uint_as_float(hi16 << 16);
}
__device__ __forceinline__ u32 f2bf(float f) {  // RNE
    u32 u = __float_as_uint(f);
    return (u + 0x7fffu + ((u >> 16) & 1u)) >> 16;
}

// ---------------- zero the 256 coarse totals ----------------

__global__ __launch_bounds__(256) void zero_tot(int* __restrict__ tot) {
    tot[threadIdx.x] = 0;
}

// ---------------- P1: coarse count (LDS hist, line-local atomics) + gemm ----
// 5120 blocks: b%5==4 -> count chunk b/5; else gemm tile (b - b/5).

__global__ __launch_bounds__(256) void p1_count_gemm(const int* __restrict__ col,
                                                     int* __restrict__ tot,
                                                     const float* __restrict__ x,
                                                     const float* __restrict__ W,
                                                     u16* __restrict__ hb) {
    __shared__ float Ws[DIM * DIM];
    __shared__ float Xs[16][DIM];
    __shared__ int lh[NCOARSE];
    const int t = threadIdx.x;
    const int b = blockIdx.x;

    if ((b % 5) == 4) {
        const int chunk = b / 5;
        lh[t] = 0;
        __syncthreads();
        const int4 c = *(const int4*)&col[chunk * 1024 + t * 4];
        atomicAdd(&lh[c.x >> 8], 1);
        atomicAdd(&lh[c.y >> 8], 1);
        atomicAdd(&lh[c.z >> 8], 1);
        atomicAdd(&lh[c.w >> 8], 1);
        __syncthreads();
        if (lh[t]) atomicAdd(&tot[t], lh[t]);   // 1KB array: line-local
    } else {
        const int row0 = (b - b / 5) * 16;
        for (int i = t; i < DIM * DIM; i += 256) Ws[i] = W[i];
        for (int i = t; i < 16 * DIM; i += 256)
            Xs[i >> 6][i & 63] = x[(size_t)(row0 + (i >> 6)) * DIM + (i & 63)];
        __syncthreads();
        const int j = t & 63;
        const int rs = t >> 6;
        for (int rr = 0; rr < 4; ++rr) {
            const int r = rs * 4 + rr;
            float acc = 0.f;
#pragma unroll
            for (int k = 0; k < DIM; ++k) acc += Xs[r][k] * Ws[k * DIM + j];
            hb[(size_t)(row0 + r) * DIM + j] = (u16)f2bf(acc);
        }
    }
}

// ---------------- P2: exclusive scan of 256 totals -> base, cursor ----------

__global__ __launch_bounds__(256) void scan256(const int* __restrict__ tot,
                                               int* __restrict__ base,
                                               int* __restrict__ cursor) {
    __shared__ int s[NCOARSE];
    const int t = threadIdx.x;
    const int my = tot[t];
    s[t] = my;
    __syncthreads();
    for (int o = 1; o < 256; o <<= 1) {
        int v = (t >= o) ? s[t - o] : 0;
        __syncthreads();
        s[t] += v;
        __syncthreads();
    }
    const int ex = s[t] - my;
    base[t] = ex;
    cursor[t] = ex;
}

// ---------------- P3: coarse multisplit scatter (LDS-sorted, run-coalesced) -
// block = 1024-edge chunk. Payload: {(row<<8)|fine, ew_bits}

__global__ __launch_bounds__(256) void p3_scatter(const int* __restrict__ col,
                                                  const int* __restrict__ row,
                                                  const float* __restrict__ ew,
                                                  int* __restrict__ cursor,
                                                  int2* __restrict__ csr_tmp) {
    __shared__ int h2[NCOARSE];
    __shared__ int base_blk[NCOARSE];
    __shared__ int off[NCOARSE];
    __shared__ int2 stg[1024];
    __shared__ int gpA[1024];
    const int t = threadIdx.x;
    const int e0 = blockIdx.x * 1024 + t * 4;

    h2[t] = 0;
    __syncthreads();

    const int4 c4 = *(const int4*)&col[e0];
    const int4 r4 = *(const int4*)&row[e0];
    const float4 w4 = *(const float4*)&ew[e0];
    const int cc[4] = {c4.x >> 8, c4.y >> 8, c4.z >> 8, c4.w >> 8};

    atomicAdd(&h2[cc[0]], 1);
    atomicAdd(&h2[cc[1]], 1);
    atomicAdd(&h2[cc[2]], 1);
    atomicAdd(&h2[cc[3]], 1);
    __syncthreads();

    const int myc = h2[t];
    off[t] = myc;
    __syncthreads();
    for (int o = 1; o < 256; o <<= 1) {           // inclusive scan
        int v = (t >= o) ? off[t - o] : 0;
        __syncthreads();
        off[t] += v;
        __syncthreads();
    }
    off[t] -= myc;                                // exclusive (own slot only)
    base_blk[t] = myc ? atomicAdd(&cursor[t], myc) : 0;  // line-local atomic
    h2[t] = 0;
    __syncthreads();

    const int fi[4] = {c4.x & 255, c4.y & 255, c4.z & 255, c4.w & 255};
    const int rr[4] = {r4.x, r4.y, r4.z, r4.w};
    const float wv[4] = {w4.x, w4.y, w4.z, w4.w};
#pragma unroll
    for (int j = 0; j < 4; ++j) {
        const int c = cc[j];
        const int r = atomicAdd(&h2[c], 1);
        const int s = off[c] + r;
        stg[s] = make_int2((rr[j] << 8) | fi[j], __float_as_int(wv[j]));
        gpA[s] = base_blk[c] + r;
    }
    __syncthreads();
    for (int i = t; i < 1024; i += 256)           // sorted order -> run-coalesced
        csr_tmp[gpA[i]] = stg[i];
}

// ---------------- P4: fine sort per coarse bucket + dinv + rowptr + premult -
// 256 blocks x 512 thr; 80KB LDS stage; final csr write fully coalesced.

__global__ __launch_bounds__(512) void p4_fine(const int* __restrict__ base,
                                               const int* __restrict__ cursor,
                                               const int2* __restrict__ csr_tmp,
                                               int2* __restrict__ csr,
                                               int* __restrict__ rowptr,
                                               float* __restrict__ dinv,
                                               u16* __restrict__ hb) {
    __shared__ int2 A[SEGCAP];
    __shared__ int2 B[SEGCAP];
    __shared__ int fh[NCOARSE];
    __shared__ int off2[NCOARSE];
    __shared__ float degw[NCOARSE];
    __shared__ float dvs[NCOARSE];
    const int t = threadIdx.x;
    const int c = blockIdx.x;
    const int seg0 = base[c];
    int segN = cursor[c] - seg0;
    if (segN > SEGCAP) segN = SEGCAP;

    for (int i = t; i < segN; i += 512) A[i] = csr_tmp[seg0 + i];
    if (t < NCOARSE) { fh[t] = 0; degw[t] = 0.f; }
    __syncthreads();

    for (int i = t; i < segN; i += 512) {
        const int f = A[i].x & 255;
        atomicAdd(&fh[f], 1);
        atomicAdd(&degw[f], __int_as_float(A[i].y));
    }
    __syncthreads();

    if (t < NCOARSE) off2[t] = fh[t];
    __syncthreads();
    for (int o = 1; o < 256; o <<= 1) {           // inclusive scan (t<256 active)
        int v = 0;
        if (t < NCOARSE && t >= o) v = off2[t - o];
        __syncthreads();
        if (t < NCOARSE) off2[t] += v;
        __syncthreads();
    }
    if (t < NCOARSE) {
        off2[t] -= fh[t];                         // exclusive
        const float dv = rsqrtf(1.0f + degw[t]);
        dvs[t] = dv;
        dinv[c * 256 + t] = dv;
        rowptr[c * 256 + t] = seg0 + off2[t];
        fh[t] = 0;                                // reset for rank pass
    }
    if (c == NCOARSE - 1 && t == 0) rowptr[N_NODES] = N_EDGES;
    __syncthreads();

    // premultiply hb rows of this block's 256 nodes by their dinv
    for (int idx = t; idx < 256 * 8; idx += 512) {
        const int nl = idx >> 3;
        const int part = idx & 7;
        const float dv = dvs[nl];
        const size_t p = (size_t)(c * 256 + nl) * DIM + part * 8;
        uint4 v = *(const uint4*)&hb[p];
        uint4 o;
        o.x = f2bf(dv * bf2f(v.x & 0xffff)) | (f2bf(dv * bf2f(v.x >> 16)) << 16);
        o.y = f2bf(dv * bf2f(v.y & 0xffff)) | (f2bf(dv * bf2f(v.y >> 16)) << 16);
        o.z = f2bf(dv * bf2f(v.z & 0xffff)) | (f2bf(dv * bf2f(v.z >> 16)) << 16);
        o.w = f2bf(dv * bf2f(v.w & 0xffff)) | (f2bf(dv * bf2f(v.w >> 16)) << 16);
        *(uint4*)&hb[p] = o;
    }

    for (int i = t; i < segN; i += 512) {
        const int f = A[i].x & 255;
        const int r = atomicAdd(&fh[f], 1);
        B[off2[f] + r] = make_int2(A[i].x >> 8, A[i].y);   // {row, ew}
    }
    __syncthreads();
    for (int i = t; i < segN; i += 512)           // fully coalesced
        csr[seg0 + i] = B[i];
}

// ---------------- aggregate layer 1 (premultiplied tables, compact csr) -----

__global__ __launch_bounds__(256) void aggregate_l1(const int* __restrict__ rowptr,
                                                    const int2* __restrict__ csr,
                                                    const u16* __restrict__ hb2,
                                                    const float* __restrict__ dinv,
                                                    const float* __restrict__ bias,
                                                    u16* __restrict__ ob) {
    const int lane = threadIdx.x & 63;
    const int node = (blockIdx.x * 256 + threadIdx.x) >> 6;
    const int g = lane >> 3;
    const int q = lane & 7;
    const int start = rowptr[node];
    const int end = rowptr[node + 1];
    const float dv = dinv[node];

    float acc[8];
#pragma unroll
    for (int k = 0; k < 8; ++k) acc[k] = 0.f;

    for (int i = start; i < end; i += 16) {
        const int i0 = i + g;
        const int i1 = i + 8 + g;
        const int2 v0 = (i0 < end) ? csr[i0] : make_int2(0, 0);
        const int2 v1 = (i1 < end) ? csr[i1] : make_int2(0, 0);
        const float w0 = __int_as_float(v0.y) * dv;
        const float w1 = __int_as_float(v1.y) * dv;
        const uint4 B0 = *(const uint4*)&hb2[(size_t)v0.x * DIM + q * 8];
        const uint4 B1 = *(const uint4*)&hb2[(size_t)v1.x * DIM + q * 8];
        acc[0] += w0 * bf2f(B0.x & 0xffff) + w1 * bf2f(B1.x & 0xffff);
        acc[1] += w0 * bf2f(B0.x >> 16)    + w1 * bf2f(B1.x >> 16);
        acc[2] += w0 * bf2f(B0.y & 0xffff) + w1 * bf2f(B1.y & 0xffff);
        acc[3] += w0 * bf2f(B0.y >> 16)    + w1 * bf2f(B1.y >> 16);
        acc[4] += w0 * bf2f(B0.z & 0xffff) + w1 * bf2f(B1.z & 0xffff);
        acc[5] += w0 * bf2f(B0.z >> 16)    + w1 * bf2f(B1.z >> 16);
        acc[6] += w0 * bf2f(B0.w & 0xffff) + w1 * bf2f(B1.w & 0xffff);
        acc[7] += w0 * bf2f(B0.w >> 16)    + w1 * bf2f(B1.w >> 16);
    }
#pragma unroll
    for (int m = 8; m <= 32; m <<= 1) {
#pragma unroll
        for (int k = 0; k < 8; ++k) acc[k] += __shfl_xor(acc[k], m, 64);
    }
    if (lane < 8) {
        const uint4 S = *(const uint4*)&hb2[(size_t)node * DIM + q * 8];
        float r[8];
        r[0] = dv * (acc[0] + dv * bf2f(S.x & 0xffff) + bias[q * 8 + 0]);
        r[1] = dv * (acc[1] + dv * bf2f(S.x >> 16)    + bias[q * 8 + 1]);
        r[2] = dv * (acc[2] + dv * bf2f(S.y & 0xffff) + bias[q * 8 + 2]);
        r[3] = dv * (acc[3] + dv * bf2f(S.y >> 16)    + bias[q * 8 + 3]);
        r[4] = dv * (acc[4] + dv * bf2f(S.z & 0xffff) + bias[q * 8 + 4]);
        r[5] = dv * (acc[5] + dv * bf2f(S.z >> 16)    + bias[q * 8 + 5]);
        r[6] = dv * (acc[6] + dv * bf2f(S.w & 0xffff) + bias[q * 8 + 6]);
        r[7] = dv * (acc[7] + dv * bf2f(S.w >> 16)    + bias[q * 8 + 7]);
        uint4 o;
        o.x = f2bf(r[0]) | (f2bf(r[1]) << 16);
        o.y = f2bf(r[2]) | (f2bf(r[3]) << 16);
        o.z = f2bf(r[4]) | (f2bf(r[5]) << 16);
        o.w = f2bf(r[6]) | (f2bf(r[7]) << 16);
        *(uint4*)&ob[(size_t)node * DIM + q * 8] = o;
    }
}

// ---------------- fused: aggregate layer 2 + pooling + W2 GEMM --------------

__global__ __launch_bounds__(512) void agg2_pool_gemm(const int* __restrict__ rowptr,
                                                      const int2* __restrict__ csr,
                                                      const u16* __restrict__ hb,
                                                      const float* __restrict__ dinv,
                                                      const float* __restrict__ W2,
                                                      const float* __restrict__ b2,
                                                      float* __restrict__ out) {
    __shared__ float Ws[DIM * DIM];
    __shared__ float wacc[8][DIM];
    __shared__ float pooled[DIM];
    const int t = threadIdx.x;
    const int m = blockIdx.x;

    for (int i = t; i < DIM * DIM; i += 512) Ws[i] = W2[i];

    const int wave = t >> 6;
    const int lane = t & 63;
    const int g = lane >> 3;
    const int q = lane & 7;

    float acc[8];
#pragma unroll
    for (int k = 0; k < 8; ++k) acc[k] = 0.f;

    const int n0 = m * 64 + wave * 8;
    for (int nn = 0; nn < 8; ++nn) {
        const int node = n0 + nn;
        const int start = rowptr[node];
        const int end = rowptr[node + 1];
        const float dv = dinv[node];
        for (int i = start; i < end; i += 16) {
            const int i0 = i + g;
            const int i1 = i + 8 + g;
            const int2 v0 = (i0 < end) ? csr[i0] : make_int2(0, 0);
            const int2 v1 = (i1 < end) ? csr[i1] : make_int2(0, 0);
            const float w0 = __int_as_float(v0.y) * dv;
            const float w1 = __int_as_float(v1.y) * dv;
            const uint4 B0 = *(const uint4*)&hb[(size_t)v0.x * DIM + q * 8];
            const uint4 B1 = *(const uint4*)&hb[(size_t)v1.x * DIM + q * 8];
            acc[0] += w0 * bf2f(B0.x & 0xffff) + w1 * bf2f(B1.x & 0xffff);
            acc[1] += w0 * bf2f(B0.x >> 16)    + w1 * bf2f(B1.x >> 16);
            acc[2] += w0 * bf2f(B0.y & 0xffff) + w1 * bf2f(B1.y & 0xffff);
            acc[3] += w0 * bf2f(B0.y >> 16)    + w1 * bf2f(B1.y >> 16);
            acc[4] += w0 * bf2f(B0.z & 0xffff) + w1 * bf2f(B1.z & 0xffff);
            acc[5] += w0 * bf2f(B0.z >> 16)    + w1 * bf2f(B1.z >> 16);
            acc[6] += w0 * bf2f(B0.w & 0xffff) + w1 * bf2f(B1.w & 0xffff);
            acc[7] += w0 * bf2f(B0.w >> 16)    + w1 * bf2f(B1.w >> 16);
        }
        if (g == 0) {  // self-loop term: dv * h1p[node]
            const uint4 S = *(const uint4*)&hb[(size_t)node * DIM + q * 8];
            acc[0] += dv * bf2f(S.x & 0xffff);
            acc[1] += dv * bf2f(S.x >> 16);
            acc[2] += dv * bf2f(S.y & 0xffff);
            acc[3] += dv * bf2f(S.y >> 16);
            acc[4] += dv * bf2f(S.z & 0xffff);
            acc[5] += dv * bf2f(S.z >> 16);
            acc[6] += dv * bf2f(S.w & 0xffff);
            acc[7] += dv * bf2f(S.w >> 16);
        }
    }
#pragma unroll
    for (int mm = 8; mm <= 32; mm <<= 1) {
#pragma unroll
        for (int k = 0; k < 8; ++k) acc[k] += __shfl_xor(acc[k], mm, 64);
    }
    if (lane < 8) {
#pragma unroll
        for (int k = 0; k < 8; ++k) wacc[wave][q * 8 + k] = acc[k];
    }
    __syncthreads();
    if (t < DIM) {
        float p = 0.f;
#pragma unroll
        for (int w = 0; w < 8; ++w) p += wacc[w][t];
        pooled[t] = p * (1.0f / DIM);
    }
    __syncthreads();
    if (t < DIM) {
        float o = b2[t];
#pragma unroll
        for (int k = 0; k < DIM; ++k) o += pooled[k] * Ws[k * DIM + t];
        out[(size_t)t * M_POOL + m] = o;
    }
}

// ---------------- launcher --------------------------------------------------

extern "C" void kernel_launch(void* const* d_in, const int* in_sizes, int n_in,
                              void* d_out, int out_size, void* d_ws, size_t ws_size,
                              hipStream_t stream) {
    const float* x  = (const float*)d_in[0];
    const int*   ei = (const int*)d_in[1];   // [2][E]
    const float* ew = (const float*)d_in[2];
    const float* W1 = (const float*)d_in[3];
    const float* b1 = (const float*)d_in[4];
    const float* W2 = (const float*)d_in[5];
    const float* b2 = (const float*)d_in[6];
    float* out = (float*)d_out;

    char* w = (char*)d_ws;
    int*   tot    = (int*)w;   w += 1024;
    int*   base   = (int*)w;   w += 1024;
    int*   cursor = (int*)w;   w += 1024;
    int*   rowptr = (int*)w;   w += (size_t)(N_NODES + 16) * 4;  // 0.25 MB
    float* dinv   = (float*)w; w += (size_t)N_NODES * 4;         // 0.25 MB
    int2*  csrt   = (int2*)w;  w += (size_t)N_EDGES * 8;         // 8 MB
    int2*  csr    = (int2*)w;  w += (size_t)N_EDGES * 8;         // 8 MB
    u16*   hbf    = (u16*)w;   w += (size_t)N_NODES * DIM * 2;   // 8 MB
    u16*   h1bf   = (u16*)w;                                     // 8 MB

    const int* row = ei;             // edge_index[0]
    const int* col = ei + N_EDGES;   // edge_index[1]

    // two-level counting-sort CSR build (line-local atomics only) + gemm
    zero_tot<<<1, 256, 0, stream>>>(tot);
    p1_count_gemm<<<5120, 256, 0, stream>>>(col, tot, x, W1, hbf);
    scan256<<<1, 256, 0, stream>>>(tot, base, cursor);
    p3_scatter<<<NCHUNK, 256, 0, stream>>>(col, row, ew, cursor, csrt);
    p4_fine<<<NCOARSE, 512, 0, stream>>>(base, cursor, csrt, csr, rowptr, dinv, hbf);

    // layer 1 aggregate: h1p = bf16(dv * (A h + b1))   (premultiplied)
    aggregate_l1<<<N_NODES / 4, 256, 0, stream>>>(rowptr, csr, hbf, dinv, b1, h1bf);

    // layer 2 + pool + W2-GEMM fused per window
    agg2_pool_gemm<<<M_POOL, 512, 0, stream>>>(rowptr, csr, h1bf, dinv, W2, b2, out);
}

// Round 11
// 155.170 us; speedup vs baseline: 1.0787x; 1.0787x over previous
//
#include <hip/hip_runtime.h>

#define N_NODES 65536
#define N_EDGES 1048576
#define DIM 64
#define M_POOL (N_NODES / DIM)  // 1024
#define NCOARSE 256             // coarse buckets (col>>8), 256 nodes each
#define NCHUNK 1024             // edge chunks of 1024 edges
#define SEGCAP 5120             // max edges per coarse bucket (mean 4096, +16 sigma)

typedef unsigned int u32;
typedef unsigned short u16;

__device__ __forceinline__ float bf2f(u32 hi16) {
    return __uint_as_float(hi16 << 16);
}
__device__ __forceinline__ u32 f2bf(float f) {  // RNE
    u32 u = __float_as_uint(f);
    return (u + 0x7fffu + ((u >> 16) & 1u)) >> 16;
}

// ---------------- zero the 256 coarse totals ----------------

__global__ __launch_bounds__(256) void zero_tot(int* __restrict__ tot) {
    tot[threadIdx.x] = 0;
}

// ---------------- P1: coarse count (LDS hist, line-local atomics) + gemm ----

__global__ __launch_bounds__(256) void p1_count_gemm(const int* __restrict__ col,
                                                     int* __restrict__ tot,
                                                     const float* __restrict__ x,
                                                     const float* __restrict__ W,
                                                     u16* __restrict__ hb) {
    __shared__ float Ws[DIM * DIM];
    __shared__ float Xs[16][DIM];
    __shared__ int lh[NCOARSE];
    const int t = threadIdx.x;
    const int b = blockIdx.x;

    if ((b % 5) == 4) {
        const int chunk = b / 5;
        lh[t] = 0;
        __syncthreads();
        const int4 c = *(const int4*)&col[chunk * 1024 + t * 4];
        atomicAdd(&lh[c.x >> 8], 1);
        atomicAdd(&lh[c.y >> 8], 1);
        atomicAdd(&lh[c.z >> 8], 1);
        atomicAdd(&lh[c.w >> 8], 1);
        __syncthreads();
        if (lh[t]) atomicAdd(&tot[t], lh[t]);   // 1KB array: line-local
    } else {
        const int row0 = (b - b / 5) * 16;
        for (int i = t; i < DIM * DIM; i += 256) Ws[i] = W[i];
        for (int i = t; i < 16 * DIM; i += 256)
            Xs[i >> 6][i & 63] = x[(size_t)(row0 + (i >> 6)) * DIM + (i & 63)];
        __syncthreads();
        const int j = t & 63;
        const int rs = t >> 6;
        for (int rr = 0; rr < 4; ++rr) {
            const int r = rs * 4 + rr;
            float acc = 0.f;
#pragma unroll
            for (int k = 0; k < DIM; ++k) acc += Xs[r][k] * Ws[k * DIM + j];
            hb[(size_t)(row0 + r) * DIM + j] = (u16)f2bf(acc);
        }
    }
}

// ---------------- P2: exclusive scan of 256 totals -> base, cursor ----------

__global__ __launch_bounds__(256) void scan256(const int* __restrict__ tot,
                                               int* __restrict__ base,
                                               int* __restrict__ cursor) {
    __shared__ int s[NCOARSE];
    const int t = threadIdx.x;
    const int my = tot[t];
    s[t] = my;
    __syncthreads();
    for (int o = 1; o < 256; o <<= 1) {
        int v = (t >= o) ? s[t - o] : 0;
        __syncthreads();
        s[t] += v;
        __syncthreads();
    }
    const int ex = s[t] - my;
    base[t] = ex;
    cursor[t] = ex;
}

// ---------------- P3: coarse multisplit scatter (LDS-sorted, run-coalesced) -

__global__ __launch_bounds__(256) void p3_scatter(const int* __restrict__ col,
                                                  const int* __restrict__ row,
                                                  const float* __restrict__ ew,
                                                  int* __restrict__ cursor,
                                                  int2* __restrict__ csr_tmp) {
    __shared__ int h2[NCOARSE];
    __shared__ int base_blk[NCOARSE];
    __shared__ int off[NCOARSE];
    __shared__ int2 stg[1024];
    __shared__ int gpA[1024];
    const int t = threadIdx.x;
    const int e0 = blockIdx.x * 1024 + t * 4;

    h2[t] = 0;
    __syncthreads();

    const int4 c4 = *(const int4*)&col[e0];
    const int4 r4 = *(const int4*)&row[e0];
    const float4 w4 = *(const float4*)&ew[e0];
    const int cc[4] = {c4.x >> 8, c4.y >> 8, c4.z >> 8, c4.w >> 8};

    atomicAdd(&h2[cc[0]], 1);
    atomicAdd(&h2[cc[1]], 1);
    atomicAdd(&h2[cc[2]], 1);
    atomicAdd(&h2[cc[3]], 1);
    __syncthreads();

    const int myc = h2[t];
    off[t] = myc;
    __syncthreads();
    for (int o = 1; o < 256; o <<= 1) {           // inclusive scan
        int v = (t >= o) ? off[t - o] : 0;
        __syncthreads();
        off[t] += v;
        __syncthreads();
    }
    off[t] -= myc;                                // exclusive (own slot only)
    base_blk[t] = myc ? atomicAdd(&cursor[t], myc) : 0;  // line-local atomic
    h2[t] = 0;
    __syncthreads();

    const int fi[4] = {c4.x & 255, c4.y & 255, c4.z & 255, c4.w & 255};
    const int rr[4] = {r4.x, r4.y, r4.z, r4.w};
    const float wv[4] = {w4.x, w4.y, w4.z, w4.w};
#pragma unroll
    for (int j = 0; j < 4; ++j) {
        const int c = cc[j];
        const int r = atomicAdd(&h2[c], 1);
        const int s = off[c] + r;
        stg[s] = make_int2((rr[j] << 8) | fi[j], __float_as_int(wv[j]));
        gpA[s] = base_blk[c] + r;
    }
    __syncthreads();
    for (int i = t; i < 1024; i += 256)           // sorted order -> run-coalesced
        csr_tmp[gpA[i]] = stg[i];
}

// ---------------- P4: fine sort + dinv + rowptr + premult (hb AND csr.y) ----
// csr.y <- ew * dv_dst  (so aggregates never touch dv of the dst per edge)

__global__ __launch_bounds__(512) void p4_fine(const int* __restrict__ base,
                                               const int* __restrict__ cursor,
                                               const int2* __restrict__ csr_tmp,
                                               int2* __restrict__ csr,
                                               int* __restrict__ rowptr,
                                               float* __restrict__ dinv,
                                               u16* __restrict__ hb) {
    __shared__ int2 A[SEGCAP];
    __shared__ int2 B[SEGCAP];
    __shared__ int fh[NCOARSE];
    __shared__ int off2[NCOARSE];
    __shared__ float degw[NCOARSE];
    __shared__ float dvs[NCOARSE];
    const int t = threadIdx.x;
    const int c = blockIdx.x;
    const int seg0 = base[c];
    int segN = cursor[c] - seg0;
    if (segN > SEGCAP) segN = SEGCAP;

    for (int i = t; i < segN; i += 512) A[i] = csr_tmp[seg0 + i];
    if (t < NCOARSE) { fh[t] = 0; degw[t] = 0.f; }
    __syncthreads();

    for (int i = t; i < segN; i += 512) {
        const int f = A[i].x & 255;
        atomicAdd(&fh[f], 1);
        atomicAdd(&degw[f], __int_as_float(A[i].y));
    }
    __syncthreads();

    if (t < NCOARSE) off2[t] = fh[t];
    __syncthreads();
    for (int o = 1; o < 256; o <<= 1) {           // inclusive scan (t<256 active)
        int v = 0;
        if (t < NCOARSE && t >= o) v = off2[t - o];
        __syncthreads();
        if (t < NCOARSE) off2[t] += v;
        __syncthreads();
    }
    if (t < NCOARSE) {
        off2[t] -= fh[t];                         // exclusive
        const float dv = rsqrtf(1.0f + degw[t]);
        dvs[t] = dv;
        dinv[c * 256 + t] = dv;
        rowptr[c * 256 + t] = seg0 + off2[t];
        fh[t] = 0;                                // reset for rank pass
    }
    if (c == NCOARSE - 1 && t == 0) rowptr[N_NODES] = N_EDGES;
    __syncthreads();

    // premultiply hb rows of this block's 256 nodes by their dinv
    for (int idx = t; idx < 256 * 8; idx += 512) {
        const int nl = idx >> 3;
        const int part = idx & 7;
        const float dv = dvs[nl];
        const size_t p = (size_t)(c * 256 + nl) * DIM + part * 8;
        uint4 v = *(const uint4*)&hb[p];
        uint4 o;
        o.x = f2bf(dv * bf2f(v.x & 0xffff)) | (f2bf(dv * bf2f(v.x >> 16)) << 16);
        o.y = f2bf(dv * bf2f(v.y & 0xffff)) | (f2bf(dv * bf2f(v.y >> 16)) << 16);
        o.z = f2bf(dv * bf2f(v.z & 0xffff)) | (f2bf(dv * bf2f(v.z >> 16)) << 16);
        o.w = f2bf(dv * bf2f(v.w & 0xffff)) | (f2bf(dv * bf2f(v.w >> 16)) << 16);
        *(uint4*)&hb[p] = o;
    }

    for (int i = t; i < segN; i += 512) {
        const int f = A[i].x & 255;
        const int r = atomicAdd(&fh[f], 1);
        // {row, ew * dv_dst}
        B[off2[f] + r] = make_int2(A[i].x >> 8,
                                   __float_as_int(__int_as_float(A[i].y) * dvs[f]));
    }
    __syncthreads();
    for (int i = t; i < segN; i += 512)           // fully coalesced
        csr[seg0 + i] = B[i];
}

// ---------------- aggregate layer 1 (csr.y premult; hb2 premult) ------------
// h1p = bf16( dv * ( sum(csr.y * hb2[r]) + dv*hb2[node] + bias ) )

__global__ __launch_bounds__(256) void aggregate_l1(const int* __restrict__ rowptr,
                                                    const int2* __restrict__ csr,
                                                    const u16* __restrict__ hb2,
                                                    const float* __restrict__ dinv,
                                                    const float* __restrict__ bias,
                                                    u16* __restrict__ ob) {
    const int lane = threadIdx.x & 63;
    const int node = (blockIdx.x * 256 + threadIdx.x) >> 6;
    const int g = lane >> 3;
    const int q = lane & 7;
    const int start = rowptr[node];
    const int end = rowptr[node + 1];
    const float dv = dinv[node];

    float acc[8];
#pragma unroll
    for (int k = 0; k < 8; ++k) acc[k] = 0.f;

    for (int i = start; i < end; i += 16) {
        const int i0 = i + g;
        const int i1 = i + 8 + g;
        const int2 v0 = (i0 < end) ? csr[i0] : make_int2(0, 0);
        const int2 v1 = (i1 < end) ? csr[i1] : make_int2(0, 0);
        const float w0 = __int_as_float(v0.y);
        const float w1 = __int_as_float(v1.y);
        const uint4 B0 = *(const uint4*)&hb2[(size_t)v0.x * DIM + q * 8];
        const uint4 B1 = *(const uint4*)&hb2[(size_t)v1.x * DIM + q * 8];
        acc[0] += w0 * bf2f(B0.x & 0xffff) + w1 * bf2f(B1.x & 0xffff);
        acc[1] += w0 * bf2f(B0.x >> 16)    + w1 * bf2f(B1.x >> 16);
        acc[2] += w0 * bf2f(B0.y & 0xffff) + w1 * bf2f(B1.y & 0xffff);
        acc[3] += w0 * bf2f(B0.y >> 16)    + w1 * bf2f(B1.y >> 16);
        acc[4] += w0 * bf2f(B0.z & 0xffff) + w1 * bf2f(B1.z & 0xffff);
        acc[5] += w0 * bf2f(B0.z >> 16)    + w1 * bf2f(B1.z >> 16);
        acc[6] += w0 * bf2f(B0.w & 0xffff) + w1 * bf2f(B1.w & 0xffff);
        acc[7] += w0 * bf2f(B0.w >> 16)    + w1 * bf2f(B1.w >> 16);
    }
#pragma unroll
    for (int m = 8; m <= 32; m <<= 1) {
#pragma unroll
        for (int k = 0; k < 8; ++k) acc[k] += __shfl_xor(acc[k], m, 64);
    }
    if (lane < 8) {
        const uint4 S = *(const uint4*)&hb2[(size_t)node * DIM + q * 8];
        float r[8];
        r[0] = dv * (acc[0] + dv * bf2f(S.x & 0xffff) + bias[q * 8 + 0]);
        r[1] = dv * (acc[1] + dv * bf2f(S.x >> 16)    + bias[q * 8 + 1]);
        r[2] = dv * (acc[2] + dv * bf2f(S.y & 0xffff) + bias[q * 8 + 2]);
        r[3] = dv * (acc[3] + dv * bf2f(S.y >> 16)    + bias[q * 8 + 3]);
        r[4] = dv * (acc[4] + dv * bf2f(S.z & 0xffff) + bias[q * 8 + 4]);
        r[5] = dv * (acc[5] + dv * bf2f(S.z >> 16)    + bias[q * 8 + 5]);
        r[6] = dv * (acc[6] + dv * bf2f(S.w & 0xffff) + bias[q * 8 + 6]);
        r[7] = dv * (acc[7] + dv * bf2f(S.w >> 16)    + bias[q * 8 + 7]);
        uint4 o;
        o.x = f2bf(r[0]) | (f2bf(r[1]) << 16);
        o.y = f2bf(r[2]) | (f2bf(r[3]) << 16);
        o.z = f2bf(r[4]) | (f2bf(r[5]) << 16);
        o.w = f2bf(r[6]) | (f2bf(r[7]) << 16);
        *(uint4*)&ob[(size_t)node * DIM + q * 8] = o;
    }
}

// ---------------- fused: layer-2 aggregate + pool + W2 GEMM (flat range) ----
// pooled[m] = (1/64)( sum_{e in [rp[64m],rp[64m+64])} csr.y_e * h1p[row_e]
//                    + sum_{c in window} dv_c * h1p[c] )
// Flat 32-edge steps per wave (4 gathers/lane in flight), no per-node logic.

__global__ __launch_bounds__(512) void agg2_pool_gemm(const int* __restrict__ rowptr,
                                                      const int2* __restrict__ csr,
                                                      const u16* __restrict__ hb,
                                                      const float* __restrict__ dinv,
                                                      const float* __restrict__ W2,
                                                      const float* __restrict__ b2,
                                                      float* __restrict__ out) {
    __shared__ float Ws[DIM * DIM];
    __shared__ float wacc[8][DIM];
    __shared__ float pooled[DIM];
    const int t = threadIdx.x;
    const int m = blockIdx.x;

    for (int i = t; i < DIM * DIM; i += 512) Ws[i] = W2[i];

    const int wave = t >> 6;
    const int lane = t & 63;
    const int g = lane >> 3;
    const int q = lane & 7;

    const int start = rowptr[m * 64];
    const int end = rowptr[m * 64 + 64];

    float acc[8];
#pragma unroll
    for (int k = 0; k < 8; ++k) acc[k] = 0.f;

    // flat edge range: 8 waves x 32 edges per step = 256 edges/block-step
    for (int i = start + wave * 32; i < end; i += 256) {
        const int i0 = i + g;
        const int i1 = i + 8 + g;
        const int i2 = i + 16 + g;
        const int i3 = i + 24 + g;
        const int2 v0 = (i0 < end) ? csr[i0] : make_int2(0, 0);
        const int2 v1 = (i1 < end) ? csr[i1] : make_int2(0, 0);
        const int2 v2 = (i2 < end) ? csr[i2] : make_int2(0, 0);
        const int2 v3 = (i3 < end) ? csr[i3] : make_int2(0, 0);
        const float w0 = __int_as_float(v0.y);
        const float w1 = __int_as_float(v1.y);
        const float w2 = __int_as_float(v2.y);
        const float w3 = __int_as_float(v3.y);
        const uint4 B0 = *(const uint4*)&hb[(size_t)v0.x * DIM + q * 8];
        const uint4 B1 = *(const uint4*)&hb[(size_t)v1.x * DIM + q * 8];
        const uint4 B2 = *(const uint4*)&hb[(size_t)v2.x * DIM + q * 8];
        const uint4 B3 = *(const uint4*)&hb[(size_t)v3.x * DIM + q * 8];
        acc[0] += w0 * bf2f(B0.x & 0xffff) + w1 * bf2f(B1.x & 0xffff)
                + w2 * bf2f(B2.x & 0xffff) + w3 * bf2f(B3.x & 0xffff);
        acc[1] += w0 * bf2f(B0.x >> 16)    + w1 * bf2f(B1.x >> 16)
                + w2 * bf2f(B2.x >> 16)    + w3 * bf2f(B3.x >> 16);
        acc[2] += w0 * bf2f(B0.y & 0xffff) + w1 * bf2f(B1.y & 0xffff)
                + w2 * bf2f(B2.y & 0xffff) + w3 * bf2f(B3.y & 0xffff);
        acc[3] += w0 * bf2f(B0.y >> 16)    + w1 * bf2f(B1.y >> 16)
                + w2 * bf2f(B2.y >> 16)    + w3 * bf2f(B3.y >> 16);
        acc[4] += w0 * bf2f(B0.z & 0xffff) + w1 * bf2f(B1.z & 0xffff)
                + w2 * bf2f(B2.z & 0xffff) + w3 * bf2f(B3.z & 0xffff);
        acc[5] += w0 * bf2f(B0.z >> 16)    + w1 * bf2f(B1.z >> 16)
                + w2 * bf2f(B2.z >> 16)    + w3 * bf2f(B3.z >> 16);
        acc[6] += w0 * bf2f(B0.w & 0xffff) + w1 * bf2f(B1.w & 0xffff)
                + w2 * bf2f(B2.w & 0xffff) + w3 * bf2f(B3.w & 0xffff);
        acc[7] += w0 * bf2f(B0.w >> 16)    + w1 * bf2f(B1.w >> 16)
                + w2 * bf2f(B2.w >> 16)    + w3 * bf2f(B3.w >> 16);
    }

    // self terms: wave handles nodes m*64 + wave*8 + g (each exactly once)
    {
        const int node = m * 64 + wave * 8 + g;
        const float dv = dinv[node];
        const uint4 S = *(const uint4*)&hb[(size_t)node * DIM + q * 8];
        acc[0] += dv * bf2f(S.x & 0xffff);
        acc[1] += dv * bf2f(S.x >> 16);
        acc[2] += dv * bf2f(S.y & 0xffff);
        acc[3] += dv * bf2f(S.y >> 16);
        acc[4] += dv * bf2f(S.z & 0xffff);
        acc[5] += dv * bf2f(S.z >> 16);
        acc[6] += dv * bf2f(S.w & 0xffff);
        acc[7] += dv * bf2f(S.w >> 16);
    }

#pragma unroll
    for (int mm = 8; mm <= 32; mm <<= 1) {
#pragma unroll
        for (int k = 0; k < 8; ++k) acc[k] += __shfl_xor(acc[k], mm, 64);
    }
    if (lane < 8) {
#pragma unroll
        for (int k = 0; k < 8; ++k) wacc[wave][q * 8 + k] = acc[k];
    }
    __syncthreads();
    if (t < DIM) {
        float p = 0.f;
#pragma unroll
        for (int w = 0; w < 8; ++w) p += wacc[w][t];
        pooled[t] = p * (1.0f / DIM);
    }
    __syncthreads();
    if (t < DIM) {
        float o = b2[t];
#pragma unroll
        for (int k = 0; k < DIM; ++k) o += pooled[k] * Ws[k * DIM + t];
        out[(size_t)t * M_POOL + m] = o;
    }
}

// ---------------- launcher --------------------------------------------------

extern "C" void kernel_launch(void* const* d_in, const int* in_sizes, int n_in,
                              void* d_out, int out_size, void* d_ws, size_t ws_size,
                              hipStream_t stream) {
    const float* x  = (const float*)d_in[0];
    const int*   ei = (const int*)d_in[1];   // [2][E]
    const float* ew = (const float*)d_in[2];
    const float* W1 = (const float*)d_in[3];
    const float* b1 = (const float*)d_in[4];
    const float* W2 = (const float*)d_in[5];
    const float* b2 = (const float*)d_in[6];
    float* out = (float*)d_out;

    char* w = (char*)d_ws;
    int*   tot    = (int*)w;   w += 1024;
    int*   base   = (int*)w;   w += 1024;
    int*   cursor = (int*)w;   w += 1024;
    int*   rowptr = (int*)w;   w += (size_t)(N_NODES + 16) * 4;  // 0.25 MB
    float* dinv   = (float*)w; w += (size_t)N_NODES * 4;         // 0.25 MB
    int2*  csrt   = (int2*)w;  w += (size_t)N_EDGES * 8;         // 8 MB
    int2*  csr    = (int2*)w;  w += (size_t)N_EDGES * 8;         // 8 MB
    u16*   hbf    = (u16*)w;   w += (size_t)N_NODES * DIM * 2;   // 8 MB
    u16*   h1bf   = (u16*)w;                                     // 8 MB

    const int* row = ei;             // edge_index[0]
    const int* col = ei + N_EDGES;   // edge_index[1]

    // two-level counting-sort CSR build (line-local atomics only) + gemm
    zero_tot<<<1, 256, 0, stream>>>(tot);
    p1_count_gemm<<<5120, 256, 0, stream>>>(col, tot, x, W1, hbf);
    scan256<<<1, 256, 0, stream>>>(tot, base, cursor);
    p3_scatter<<<NCHUNK, 256, 0, stream>>>(col, row, ew, cursor, csrt);
    p4_fine<<<NCOARSE, 512, 0, stream>>>(base, cursor, csrt, csr, rowptr, dinv, hbf);

    // layer 1 aggregate: h1p = bf16(dv * (A h + b1))   (premultiplied)
    aggregate_l1<<<N_NODES / 4, 256, 0, stream>>>(rowptr, csr, hbf, dinv, b1, h1bf);

    // layer 2 + pool + W2-GEMM fused per window (flat contiguous edge range)
    agg2_pool_gemm<<<M_POOL, 512, 0, stream>>>(rowptr, csr, h1bf, dinv, W2, b2, out);
}

// Round 12
// 137.184 us; speedup vs baseline: 1.2201x; 1.1311x over previous
//
#include <hip/hip_runtime.h>

#define N_NODES 65536
#define N_EDGES 1048576
#define DIM 64
#define M_POOL (N_NODES / DIM)  // 1024
#define NCOARSE 256             // coarse buckets (col>>8), 256 nodes each
#define SEGCAP 5120             // fixed region per coarse bucket (mean 4096 + 16 sigma)
#define P3CHUNK 4096            // edges per p3 block
#define P3BLOCKS (N_EDGES / P3CHUNK)  // 256

typedef unsigned int u32;
typedef unsigned short u16;

__device__ __forceinline__ float bf2f(u32 hi16) {
    return __uint_as_float(hi16 << 16);
}
__device__ __forceinline__ u32 f2bf(float f) {  // RNE
    u32 u = __float_as_uint(f);
    return (u + 0x7fffu + ((u >> 16) & 1u)) >> 16;
}

// ---------------- zero the 256 coarse cursors ----------------

__global__ __launch_bounds__(256) void zero_cursor(int* __restrict__ cursor) {
    cursor[threadIdx.x] = 0;
}

// ---------------- GEMM: hb = bf16(x @ W1) -----------------------------------

__global__ __launch_bounds__(256) void gemm64(const float* __restrict__ xin,
                                              const float* __restrict__ W,
                                              u16* __restrict__ hb) {
    __shared__ float Ws[DIM * DIM];
    __shared__ float Xs[16][DIM];
    const int tid = threadIdx.x;
    const int row0 = blockIdx.x * 16;

    for (int i = tid; i < DIM * DIM; i += 256) Ws[i] = W[i];
    for (int i = tid; i < 16 * DIM; i += 256)
        Xs[i >> 6][i & 63] = xin[(size_t)(row0 + (i >> 6)) * DIM + (i & 63)];
    __syncthreads();

    const int j = tid & 63;
    const int rs = tid >> 6;
    for (int rr = 0; rr < 4; ++rr) {
        const int r = rs * 4 + rr;
        float acc = 0.f;
#pragma unroll
        for (int k = 0; k < DIM; ++k) acc += Xs[r][k] * Ws[k * DIM + j];
        hb[(size_t)(row0 + r) * DIM + j] = (u16)f2bf(acc);
    }
}

// ---------------- P3: coarse multisplit into fixed-capacity regions ---------
// 256 blocks x 1024 thr, 4096 edges/block. Payload {(row<<8)|fine, ew_bits}.
// csr_tmp[c*SEGCAP + cursor-offset]; LDS-sorted staging -> run-coalesced writes.

__global__ __launch_bounds__(1024) void p3_scatter(const int* __restrict__ col,
                                                   const int* __restrict__ row,
                                                   const float* __restrict__ ew,
                                                   int* __restrict__ cursor,
                                                   int2* __restrict__ csr_tmp) {
    __shared__ int h2[NCOARSE];
    __shared__ int base_blk[NCOARSE];
    __shared__ int off[NCOARSE];
    __shared__ int2 stg[P3CHUNK];
    __shared__ int gpA[P3CHUNK];
    const int t = threadIdx.x;
    const int e0 = blockIdx.x * P3CHUNK + t * 4;

    if (t < NCOARSE) h2[t] = 0;
    __syncthreads();

    const int4 c4 = *(const int4*)&col[e0];
    const int4 r4 = *(const int4*)&row[e0];
    const float4 w4 = *(const float4*)&ew[e0];
    const int cc[4] = {c4.x >> 8, c4.y >> 8, c4.z >> 8, c4.w >> 8};

    atomicAdd(&h2[cc[0]], 1);
    atomicAdd(&h2[cc[1]], 1);
    atomicAdd(&h2[cc[2]], 1);
    atomicAdd(&h2[cc[3]], 1);
    __syncthreads();

    const int myc = (t < NCOARSE) ? h2[t] : 0;
    if (t < NCOARSE) off[t] = myc;
    __syncthreads();
    for (int o = 1; o < NCOARSE; o <<= 1) {       // inclusive scan (t<256 active)
        int v = 0;
        if (t < NCOARSE && t >= o) v = off[t - o];
        __syncthreads();
        if (t < NCOARSE) off[t] += v;
        __syncthreads();
    }
    if (t < NCOARSE) {
        off[t] -= myc;                            // exclusive
        base_blk[t] = myc ? atomicAdd(&cursor[t], myc) : 0;
        h2[t] = 0;
    }
    __syncthreads();

    const int fi[4] = {c4.x & 255, c4.y & 255, c4.z & 255, c4.w & 255};
    const int rr[4] = {r4.x, r4.y, r4.z, r4.w};
    const float wv[4] = {w4.x, w4.y, w4.z, w4.w};
#pragma unroll
    for (int j = 0; j < 4; ++j) {
        const int c = cc[j];
        const int r = atomicAdd(&h2[c], 1);
        const int s = off[c] + r;
        const int bp = base_blk[c] + r;
        stg[s] = make_int2((rr[j] << 8) | fi[j], __float_as_int(wv[j]));
        gpA[s] = (bp < SEGCAP) ? (c * SEGCAP + bp) : -1;
    }
    __syncthreads();
    for (int i = t; i < P3CHUNK; i += 1024) {     // sorted order -> run-coalesced
        const int gp = gpA[i];
        if (gp >= 0) csr_tmp[gp] = stg[i];
    }
}

// ---------------- scan of clamped cursors -> compact output bases -----------

__global__ __launch_bounds__(256) void scan256(const int* __restrict__ cursor,
                                               int* __restrict__ base) {
    __shared__ int s[NCOARSE];
    const int t = threadIdx.x;
    const int my = min(cursor[t], SEGCAP);
    s[t] = my;
    __syncthreads();
    for (int o = 1; o < 256; o <<= 1) {
        int v = (t >= o) ? s[t - o] : 0;
        __syncthreads();
        s[t] += v;
        __syncthreads();
    }
    base[t] = s[t] - my;
}

// ---------------- P4: fine sort + dinv + rowptr + premult (hb AND csr.y) ----
// csr.y <- ew * dv_dst  (aggregates never gather dst's dv per edge)

__global__ __launch_bounds__(512) void p4_fine(const int* __restrict__ base,
                                               const int* __restrict__ cursor,
                                               const int2* __restrict__ csr_tmp,
                                               int2* __restrict__ csr,
                                               int* __restrict__ rowptr,
                                               float* __restrict__ dinv,
                                               u16* __restrict__ hb) {
    __shared__ int2 A[SEGCAP];
    __shared__ int2 B[SEGCAP];
    __shared__ int fh[NCOARSE];
    __shared__ int off2[NCOARSE];
    __shared__ float degw[NCOARSE];
    __shared__ float dvs[NCOARSE];
    const int t = threadIdx.x;
    const int c = blockIdx.x;
    const int seg0_out = base[c];
    const int segN = min(cursor[c], SEGCAP);

    for (int i = t; i < segN; i += 512) A[i] = csr_tmp[c * SEGCAP + i];
    if (t < NCOARSE) { fh[t] = 0; degw[t] = 0.f; }
    __syncthreads();

    for (int i = t; i < segN; i += 512) {
        const int f = A[i].x & 255;
        atomicAdd(&fh[f], 1);
        atomicAdd(&degw[f], __int_as_float(A[i].y));
    }
    __syncthreads();

    if (t < NCOARSE) off2[t] = fh[t];
    __syncthreads();
    for (int o = 1; o < 256; o <<= 1) {           // inclusive scan (t<256 active)
        int v = 0;
        if (t < NCOARSE && t >= o) v = off2[t - o];
        __syncthreads();
        if (t < NCOARSE) off2[t] += v;
        __syncthreads();
    }
    if (t < NCOARSE) {
        off2[t] -= fh[t];                         // exclusive
        const float dv = rsqrtf(1.0f + degw[t]);
        dvs[t] = dv;
        dinv[c * 256 + t] = dv;
        rowptr[c * 256 + t] = seg0_out + off2[t];
        fh[t] = 0;                                // reset for rank pass
    }
    if (c == NCOARSE - 1 && t == 0) rowptr[N_NODES] = seg0_out + segN;
    __syncthreads();

    // premultiply hb rows of this block's 256 nodes by their dinv
    for (int idx = t; idx < 256 * 8; idx += 512) {
        const int nl = idx >> 3;
        const int part = idx & 7;
        const float dv = dvs[nl];
        const size_t p = (size_t)(c * 256 + nl) * DIM + part * 8;
        uint4 v = *(const uint4*)&hb[p];
        uint4 o;
        o.x = f2bf(dv * bf2f(v.x & 0xffff)) | (f2bf(dv * bf2f(v.x >> 16)) << 16);
        o.y = f2bf(dv * bf2f(v.y & 0xffff)) | (f2bf(dv * bf2f(v.y >> 16)) << 16);
        o.z = f2bf(dv * bf2f(v.z & 0xffff)) | (f2bf(dv * bf2f(v.z >> 16)) << 16);
        o.w = f2bf(dv * bf2f(v.w & 0xffff)) | (f2bf(dv * bf2f(v.w >> 16)) << 16);
        *(uint4*)&hb[p] = o;
    }

    for (int i = t; i < segN; i += 512) {
        const int f = A[i].x & 255;
        const int r = atomicAdd(&fh[f], 1);
        // {row, ew * dv_dst}
        B[off2[f] + r] = make_int2(A[i].x >> 8,
                                   __float_as_int(__int_as_float(A[i].y) * dvs[f]));
    }
    __syncthreads();
    for (int i = t; i < segN; i += 512)           // fully coalesced
        csr[seg0_out + i] = B[i];
}

// ---------------- aggregate layer 1 (csr.y premult; hb2 premult) ------------
// h1p = bf16( dv * ( sum(csr.y * hb2[r]) + dv*hb2[node] + bias ) )

__global__ __launch_bounds__(256) void aggregate_l1(const int* __restrict__ rowptr,
                                                    const int2* __restrict__ csr,
                                                    const u16* __restrict__ hb2,
                                                    const float* __restrict__ dinv,
                                                    const float* __restrict__ bias,
                                                    u16* __restrict__ ob) {
    const int lane = threadIdx.x & 63;
    const int node = (blockIdx.x * 256 + threadIdx.x) >> 6;
    const int g = lane >> 3;
    const int q = lane & 7;
    const int start = rowptr[node];
    const int end = rowptr[node + 1];
    const float dv = dinv[node];

    float acc[8];
#pragma unroll
    for (int k = 0; k < 8; ++k) acc[k] = 0.f;

    for (int i = start; i < end; i += 16) {
        const int i0 = i + g;
        const int i1 = i + 8 + g;
        const int2 v0 = (i0 < end) ? csr[i0] : make_int2(0, 0);
        const int2 v1 = (i1 < end) ? csr[i1] : make_int2(0, 0);
        const float w0 = __int_as_float(v0.y);
        const float w1 = __int_as_float(v1.y);
        const uint4 B0 = *(const uint4*)&hb2[(size_t)v0.x * DIM + q * 8];
        const uint4 B1 = *(const uint4*)&hb2[(size_t)v1.x * DIM + q * 8];
        acc[0] += w0 * bf2f(B0.x & 0xffff) + w1 * bf2f(B1.x & 0xffff);
        acc[1] += w0 * bf2f(B0.x >> 16)    + w1 * bf2f(B1.x >> 16);
        acc[2] += w0 * bf2f(B0.y & 0xffff) + w1 * bf2f(B1.y & 0xffff);
        acc[3] += w0 * bf2f(B0.y >> 16)    + w1 * bf2f(B1.y >> 16);
        acc[4] += w0 * bf2f(B0.z & 0xffff) + w1 * bf2f(B1.z & 0xffff);
        acc[5] += w0 * bf2f(B0.z >> 16)    + w1 * bf2f(B1.z >> 16);
        acc[6] += w0 * bf2f(B0.w & 0xffff) + w1 * bf2f(B1.w & 0xffff);
        acc[7] += w0 * bf2f(B0.w >> 16)    + w1 * bf2f(B1.w >> 16);
    }
#pragma unroll
    for (int m = 8; m <= 32; m <<= 1) {
#pragma unroll
        for (int k = 0; k < 8; ++k) acc[k] += __shfl_xor(acc[k], m, 64);
    }
    if (lane < 8) {
        const uint4 S = *(const uint4*)&hb2[(size_t)node * DIM + q * 8];
        float r[8];
        r[0] = dv * (acc[0] + dv * bf2f(S.x & 0xffff) + bias[q * 8 + 0]);
        r[1] = dv * (acc[1] + dv * bf2f(S.x >> 16)    + bias[q * 8 + 1]);
        r[2] = dv * (acc[2] + dv * bf2f(S.y & 0xffff) + bias[q * 8 + 2]);
        r[3] = dv * (acc[3] + dv * bf2f(S.y >> 16)    + bias[q * 8 + 3]);
        r[4] = dv * (acc[4] + dv * bf2f(S.z & 0xffff) + bias[q * 8 + 4]);
        r[5] = dv * (acc[5] + dv * bf2f(S.z >> 16)    + bias[q * 8 + 5]);
        r[6] = dv * (acc[6] + dv * bf2f(S.w & 0xffff) + bias[q * 8 + 6]);
        r[7] = dv * (acc[7] + dv * bf2f(S.w >> 16)    + bias[q * 8 + 7]);
        uint4 o;
        o.x = f2bf(r[0]) | (f2bf(r[1]) << 16);
        o.y = f2bf(r[2]) | (f2bf(r[3]) << 16);
        o.z = f2bf(r[4]) | (f2bf(r[5]) << 16);
        o.w = f2bf(r[6]) | (f2bf(r[7]) << 16);
        *(uint4*)&ob[(size_t)node * DIM + q * 8] = o;
    }
}

// ---------------- fused: layer-2 aggregate + pool + W2 GEMM (flat range) ----

__global__ __launch_bounds__(512) void agg2_pool_gemm(const int* __restrict__ rowptr,
                                                      const int2* __restrict__ csr,
                                                      const u16* __restrict__ hb,
                                                      const float* __restrict__ dinv,
                                                      const float* __restrict__ W2,
                                                      const float* __restrict__ b2,
                                                      float* __restrict__ out) {
    __shared__ float Ws[DIM * DIM];
    __shared__ float wacc[8][DIM];
    __shared__ float pooled[DIM];
    const int t = threadIdx.x;
    const int m = blockIdx.x;

    for (int i = t; i < DIM * DIM; i += 512) Ws[i] = W2[i];

    const int wave = t >> 6;
    const int lane = t & 63;
    const int g = lane >> 3;
    const int q = lane & 7;

    const int start = rowptr[m * 64];
    const int end = rowptr[m * 64 + 64];

    float acc[8];
#pragma unroll
    for (int k = 0; k < 8; ++k) acc[k] = 0.f;

    for (int i = start + wave * 32; i < end; i += 256) {
        const int i0 = i + g;
        const int i1 = i + 8 + g;
        const int i2 = i + 16 + g;
        const int i3 = i + 24 + g;
        const int2 v0 = (i0 < end) ? csr[i0] : make_int2(0, 0);
        const int2 v1 = (i1 < end) ? csr[i1] : make_int2(0, 0);
        const int2 v2 = (i2 < end) ? csr[i2] : make_int2(0, 0);
        const int2 v3 = (i3 < end) ? csr[i3] : make_int2(0, 0);
        const float w0 = __int_as_float(v0.y);
        const float w1 = __int_as_float(v1.y);
        const float w2 = __int_as_float(v2.y);
        const float w3 = __int_as_float(v3.y);
        const uint4 B0 = *(const uint4*)&hb[(size_t)v0.x * DIM + q * 8];
        const uint4 B1 = *(const uint4*)&hb[(size_t)v1.x * DIM + q * 8];
        const uint4 B2 = *(const uint4*)&hb[(size_t)v2.x * DIM + q * 8];
        const uint4 B3 = *(const uint4*)&hb[(size_t)v3.x * DIM + q * 8];
        acc[0] += w0 * bf2f(B0.x & 0xffff) + w1 * bf2f(B1.x & 0xffff)
                + w2 * bf2f(B2.x & 0xffff) + w3 * bf2f(B3.x & 0xffff);
        acc[1] += w0 * bf2f(B0.x >> 16)    + w1 * bf2f(B1.x >> 16)
                + w2 * bf2f(B2.x >> 16)    + w3 * bf2f(B3.x >> 16);
        acc[2] += w0 * bf2f(B0.y & 0xffff) + w1 * bf2f(B1.y & 0xffff)
                + w2 * bf2f(B2.y & 0xffff) + w3 * bf2f(B3.y & 0xffff);
        acc[3] += w0 * bf2f(B0.y >> 16)    + w1 * bf2f(B1.y >> 16)
                + w2 * bf2f(B2.y >> 16)    + w3 * bf2f(B3.y >> 16);
        acc[4] += w0 * bf2f(B0.z & 0xffff) + w1 * bf2f(B1.z & 0xffff)
                + w2 * bf2f(B2.z & 0xffff) + w3 * bf2f(B3.z & 0xffff);
        acc[5] += w0 * bf2f(B0.z >> 16)    + w1 * bf2f(B1.z >> 16)
                + w2 * bf2f(B2.z >> 16)    + w3 * bf2f(B3.z >> 16);
        acc[6] += w0 * bf2f(B0.w & 0xffff) + w1 * bf2f(B1.w & 0xffff)
                + w2 * bf2f(B2.w & 0xffff) + w3 * bf2f(B3.w & 0xffff);
        acc[7] += w0 * bf2f(B0.w >> 16)    + w1 * bf2f(B1.w >> 16)
                + w2 * bf2f(B2.w >> 16)    + w3 * bf2f(B3.w >> 16);
    }

    // self terms: wave handles nodes m*64 + wave*8 + g (each exactly once)
    {
        const int node = m * 64 + wave * 8 + g;
        const float dv = dinv[node];
        const uint4 S = *(const uint4*)&hb[(size_t)node * DIM + q * 8];
        acc[0] += dv * bf2f(S.x & 0xffff);
        acc[1] += dv * bf2f(S.x >> 16);
        acc[2] += dv * bf2f(S.y & 0xffff);
        acc[3] += dv * bf2f(S.y >> 16);
        acc[4] += dv * bf2f(S.z & 0xffff);
        acc[5] += dv * bf2f(S.z >> 16);
        acc[6] += dv * bf2f(S.w & 0xffff);
        acc[7] += dv * bf2f(S.w >> 16);
    }

#pragma unroll
    for (int mm = 8; mm <= 32; mm <<= 1) {
#pragma unroll
        for (int k = 0; k < 8; ++k) acc[k] += __shfl_xor(acc[k], mm, 64);
    }
    if (lane < 8) {
#pragma unroll
        for (int k = 0; k < 8; ++k) wacc[wave][q * 8 + k] = acc[k];
    }
    __syncthreads();
    if (t < DIM) {
        float p = 0.f;
#pragma unroll
        for (int w = 0; w < 8; ++w) p += wacc[w][t];
        pooled[t] = p * (1.0f / DIM);
    }
    __syncthreads();
    if (t < DIM) {
        float o = b2[t];
#pragma unroll
        for (int k = 0; k < DIM; ++k) o += pooled[k] * Ws[k * DIM + t];
        out[(size_t)t * M_POOL + m] = o;
    }
}

// ---------------- launcher --------------------------------------------------

extern "C" void kernel_launch(void* const* d_in, const int* in_sizes, int n_in,
                              void* d_out, int out_size, void* d_ws, size_t ws_size,
                              hipStream_t stream) {
    const float* x  = (const float*)d_in[0];
    const int*   ei = (const int*)d_in[1];   // [2][E]
    const float* ew = (const float*)d_in[2];
    const float* W1 = (const float*)d_in[3];
    const float* b1 = (const float*)d_in[4];
    const float* W2 = (const float*)d_in[5];
    const float* b2 = (const float*)d_in[6];
    float* out = (float*)d_out;

    char* w = (char*)d_ws;
    int*   cursor = (int*)w;   w += 1024;
    int*   base   = (int*)w;   w += 1024;
    int*   rowptr = (int*)w;   w += (size_t)(N_NODES + 16) * 4;      // 0.25 MB
    float* dinv   = (float*)w; w += (size_t)N_NODES * 4;             // 0.25 MB
    int2*  csrt   = (int2*)w;  w += (size_t)NCOARSE * SEGCAP * 8;    // 10.5 MB
    int2*  csr    = (int2*)w;  w += (size_t)N_EDGES * 8;             // 8 MB
    u16*   hbf    = (u16*)w;   w += (size_t)N_NODES * DIM * 2;       // 8 MB
    u16*   h1bf   = (u16*)w;                                         // 8 MB

    const int* row = ei;             // edge_index[0]
    const int* col = ei + N_EDGES;   // edge_index[1]

    // CSR build: fixed-capacity coarse regions (no count pass, no pre-scan)
    zero_cursor<<<1, 256, 0, stream>>>(cursor);
    gemm64<<<N_NODES / 16, 256, 0, stream>>>(x, W1, hbf);
    p3_scatter<<<P3BLOCKS, 1024, 0, stream>>>(col, row, ew, cursor, csrt);
    scan256<<<1, 256, 0, stream>>>(cursor, base);
    p4_fine<<<NCOARSE, 512, 0, stream>>>(base, cursor, csrt, csr, rowptr, dinv, hbf);

    // layer 1 aggregate: h1p = bf16(dv * (A h + b1))   (premultiplied)
    aggregate_l1<<<N_NODES / 4, 256, 0, stream>>>(rowptr, csr, hbf, dinv, b1, h1bf);

    // layer 2 + pool + W2-GEMM fused per window (flat contiguous edge range)
    agg2_pool_gemm<<<M_POOL, 512, 0, stream>>>(rowptr, csr, h1bf, dinv, W2, b2, out);
}

// Round 13
// 121.344 us; speedup vs baseline: 1.3794x; 1.1305x over previous
//
#include <hip/hip_runtime.h>

#define N_NODES 65536
#define N_EDGES 1048576
#define DIM 64
#define M_POOL (N_NODES / DIM)  // 1024
#define NCOARSE 256             // coarse buckets (col>>8), 256 nodes each
#define SEGCAP 5120             // fixed region per coarse bucket (mean 4096 + 16 sigma)
#define P3CHUNK 4096            // edges per p3 block
#define P3BLOCKS (N_EDGES / P3CHUNK)   // 256
#define GEMM_BLOCKS 1024               // 65536 rows / 64 per block
#define FUSED_BLOCKS (GEMM_BLOCKS + P3BLOCKS)  // 1280, 4:1 interleave

typedef unsigned int u32;
typedef unsigned short u16;

__device__ __forceinline__ float bf2f(u32 hi16) {
    return __uint_as_float(hi16 << 16);
}
__device__ __forceinline__ u32 f2bf(float f) {  // RNE
    u32 u = __float_as_uint(f);
    return (u + 0x7fffu + ((u >> 16) & 1u)) >> 16;
}

// ---------------- zero the 256 coarse cursors ----------------

__global__ __launch_bounds__(256) void zero_cursor(int* __restrict__ cursor) {
    cursor[threadIdx.x] = 0;
}

// ---------------- fused: layer-1 GEMM || coarse multisplit scatter ----------
// 1280 blocks x 1024 thr. b%5==4 -> p3 chunk b/5 (4096 edges); else gemm tile
// (b - b/5)*64 rows. Independent phases share an LDS union buffer.

__global__ __launch_bounds__(1024) void fused_gemm_p3(const float* __restrict__ x,
                                                      const float* __restrict__ W,
                                                      u16* __restrict__ hb,
                                                      const int* __restrict__ col,
                                                      const int* __restrict__ row,
                                                      const float* __restrict__ ew,
                                                      int* __restrict__ cursor,
                                                      int2* __restrict__ csr_tmp) {
    __shared__ __align__(16) char sm[52224];
    const int t = threadIdx.x;
    const int b = blockIdx.x;

    if ((b % 5) == 4) {
        // ---- p3 block: coarse multisplit of chunk b/5 ----
        int2* stg      = (int2*)sm;              // 32768 B
        int*  gpA      = (int*)(sm + 32768);     // 16384 B
        int*  h2       = (int*)(sm + 49152);     // 1024 B
        int*  off      = (int*)(sm + 50176);     // 1024 B
        int*  base_blk = (int*)(sm + 51200);     // 1024 B
        const int e0 = (b / 5) * P3CHUNK + t * 4;

        if (t < NCOARSE) h2[t] = 0;
        __syncthreads();

        const int4 c4 = *(const int4*)&col[e0];
        const int4 r4 = *(const int4*)&row[e0];
        const float4 w4 = *(const float4*)&ew[e0];
        const int cc[4] = {c4.x >> 8, c4.y >> 8, c4.z >> 8, c4.w >> 8};

        atomicAdd(&h2[cc[0]], 1);
        atomicAdd(&h2[cc[1]], 1);
        atomicAdd(&h2[cc[2]], 1);
        atomicAdd(&h2[cc[3]], 1);
        __syncthreads();

        const int myc = (t < NCOARSE) ? h2[t] : 0;
        if (t < NCOARSE) off[t] = myc;
        __syncthreads();
        for (int o = 1; o < NCOARSE; o <<= 1) {   // inclusive scan (t<256 active)
            int v = 0;
            if (t < NCOARSE && t >= o) v = off[t - o];
            __syncthreads();
            if (t < NCOARSE) off[t] += v;
            __syncthreads();
        }
        if (t < NCOARSE) {
            off[t] -= myc;                        // exclusive
            base_blk[t] = myc ? atomicAdd(&cursor[t], myc) : 0;
            h2[t] = 0;
        }
        __syncthreads();

        const int fi[4] = {c4.x & 255, c4.y & 255, c4.z & 255, c4.w & 255};
        const int rr[4] = {r4.x, r4.y, r4.z, r4.w};
        const float wv[4] = {w4.x, w4.y, w4.z, w4.w};
#pragma unroll
        for (int j = 0; j < 4; ++j) {
            const int c = cc[j];
            const int r = atomicAdd(&h2[c], 1);
            const int s = off[c] + r;
            const int bp = base_blk[c] + r;
            stg[s] = make_int2((rr[j] << 8) | fi[j], __float_as_int(wv[j]));
            gpA[s] = (bp < SEGCAP) ? (c * SEGCAP + bp) : -1;
        }
        __syncthreads();
        for (int i = t; i < P3CHUNK; i += 1024) { // sorted order -> run-coalesced
            const int gp = gpA[i];
            if (gp >= 0) csr_tmp[gp] = stg[i];
        }
    } else {
        // ---- gemm block: 64 rows, hb = bf16(x @ W1) ----
        float* Ws = (float*)sm;                   // 16 KB
        float* Xs = (float*)(sm + 16384);         // 16 KB: [64][64]
        const int row0 = (b - b / 5) * 64;
        for (int i = t; i < DIM * DIM; i += 1024) Ws[i] = W[i];
        for (int i = t; i < 64 * DIM; i += 1024)
            Xs[i] = x[(size_t)row0 * DIM + i];
        __syncthreads();
        const int j = t & 63;
        const int rs = t >> 6;                    // 0..15
        for (int rrr = 0; rrr < 4; ++rrr) {
            const int r = rs * 4 + rrr;
            float acc = 0.f;
#pragma unroll
            for (int k = 0; k < DIM; ++k) acc += Xs[r * DIM + k] * Ws[k * DIM + j];
            hb[(size_t)(row0 + r) * DIM + j] = (u16)f2bf(acc);
        }
    }
}

// ---------------- P4: fine sort + dinv + rowptr + premult; 4B csr out -------
// Inlined cursor scan (no scan256 kernel). csr entry = {bf16(ew*dv_dst)<<16 | src}

__global__ __launch_bounds__(512) void p4_fine(const int* __restrict__ cursor,
                                               const int2* __restrict__ csr_tmp,
                                               u32* __restrict__ csr,
                                               int* __restrict__ rowptr,
                                               float* __restrict__ dinv,
                                               u16* __restrict__ hb) {
    __shared__ int2 A[SEGCAP];          // 40 KB
    __shared__ u32 Bu[SEGCAP];          // 20 KB
    __shared__ int fh[NCOARSE];
    __shared__ int off2[NCOARSE];
    __shared__ int cbase[NCOARSE];
    __shared__ float degw[NCOARSE];
    __shared__ float dvs[NCOARSE];
    const int t = threadIdx.x;
    const int c = blockIdx.x;
    const int segN = min(cursor[c], SEGCAP);

    // inclusive scan of clamped cursors -> output base for bucket c
    if (t < NCOARSE) cbase[t] = min(cursor[t], SEGCAP);
    __syncthreads();
    for (int o = 1; o < NCOARSE; o <<= 1) {
        int v = 0;
        if (t < NCOARSE && t >= o) v = cbase[t - o];
        __syncthreads();
        if (t < NCOARSE) cbase[t] += v;
        __syncthreads();
    }
    const int seg0_out = cbase[c] - segN;

    for (int i = t; i < segN; i += 512) A[i] = csr_tmp[c * SEGCAP + i];
    if (t < NCOARSE) { fh[t] = 0; degw[t] = 0.f; }
    __syncthreads();

    for (int i = t; i < segN; i += 512) {
        const int f = A[i].x & 255;
        atomicAdd(&fh[f], 1);
        atomicAdd(&degw[f], __int_as_float(A[i].y));
    }
    __syncthreads();

    if (t < NCOARSE) off2[t] = fh[t];
    __syncthreads();
    for (int o = 1; o < NCOARSE; o <<= 1) {       // inclusive scan (t<256 active)
        int v = 0;
        if (t < NCOARSE && t >= o) v = off2[t - o];
        __syncthreads();
        if (t < NCOARSE) off2[t] += v;
        __syncthreads();
    }
    if (t < NCOARSE) {
        off2[t] -= fh[t];                         // exclusive
        const float dv = rsqrtf(1.0f + degw[t]);
        dvs[t] = dv;
        dinv[c * 256 + t] = dv;
        rowptr[c * 256 + t] = seg0_out + off2[t];
        fh[t] = 0;                                // reset for rank pass
    }
    if (c == NCOARSE - 1 && t == 0) rowptr[N_NODES] = seg0_out + segN;
    __syncthreads();

    // premultiply hb rows of this bucket's 256 nodes by their dinv
    for (int idx = t; idx < 256 * 8; idx += 512) {
        const int nl = idx >> 3;
        const int part = idx & 7;
        const float dv = dvs[nl];
        const size_t p = (size_t)(c * 256 + nl) * DIM + part * 8;
        uint4 v = *(const uint4*)&hb[p];
        uint4 o;
        o.x = f2bf(dv * bf2f(v.x & 0xffff)) | (f2bf(dv * bf2f(v.x >> 16)) << 16);
        o.y = f2bf(dv * bf2f(v.y & 0xffff)) | (f2bf(dv * bf2f(v.y >> 16)) << 16);
        o.z = f2bf(dv * bf2f(v.z & 0xffff)) | (f2bf(dv * bf2f(v.z >> 16)) << 16);
        o.w = f2bf(dv * bf2f(v.w & 0xffff)) | (f2bf(dv * bf2f(v.w >> 16)) << 16);
        *(uint4*)&hb[p] = o;
    }

    for (int i = t; i < segN; i += 512) {
        const int f = A[i].x & 255;
        const int r = atomicAdd(&fh[f], 1);
        const float w = __int_as_float(A[i].y) * dvs[f];
        Bu[off2[f] + r] = (f2bf(w) << 16) | ((u32)(A[i].x >> 8) & 0xffffu);
    }
    __syncthreads();
    for (int i = t; i < segN; i += 512)           // fully coalesced
        csr[seg0_out + i] = Bu[i];
}

// ---------------- aggregate layer 1 (4B csr; premult tables) ----------------
// h1p = bf16( dv * ( sum(w_e * hb2[src_e]) + dv*hb2[node] + bias ) )

__global__ __launch_bounds__(256) void aggregate_l1(const int* __restrict__ rowptr,
                                                    const u32* __restrict__ csr,
                                                    const u16* __restrict__ hb2,
                                                    const float* __restrict__ dinv,
                                                    const float* __restrict__ bias,
                                                    u16* __restrict__ ob) {
    const int lane = threadIdx.x & 63;
    const int node = (blockIdx.x * 256 + threadIdx.x) >> 6;
    const int g = lane >> 3;
    const int q = lane & 7;
    const int start = rowptr[node];
    const int end = rowptr[node + 1];
    const float dv = dinv[node];

    float acc[8];
#pragma unroll
    for (int k = 0; k < 8; ++k) acc[k] = 0.f;

    for (int i = start; i < end; i += 16) {
        const int i0 = i + g;
        const int i1 = i + 8 + g;
        const u32 v0 = (i0 < end) ? csr[i0] : 0;
        const u32 v1 = (i1 < end) ? csr[i1] : 0;
        const float w0 = bf2f(v0 >> 16);
        const float w1 = bf2f(v1 >> 16);
        const uint4 B0 = *(const uint4*)&hb2[(size_t)(v0 & 0xffffu) * DIM + q * 8];
        const uint4 B1 = *(const uint4*)&hb2[(size_t)(v1 & 0xffffu) * DIM + q * 8];
        acc[0] += w0 * bf2f(B0.x & 0xffff) + w1 * bf2f(B1.x & 0xffff);
        acc[1] += w0 * bf2f(B0.x >> 16)    + w1 * bf2f(B1.x >> 16);
        acc[2] += w0 * bf2f(B0.y & 0xffff) + w1 * bf2f(B1.y & 0xffff);
        acc[3] += w0 * bf2f(B0.y >> 16)    + w1 * bf2f(B1.y >> 16);
        acc[4] += w0 * bf2f(B0.z & 0xffff) + w1 * bf2f(B1.z & 0xffff);
        acc[5] += w0 * bf2f(B0.z >> 16)    + w1 * bf2f(B1.z >> 16);
        acc[6] += w0 * bf2f(B0.w & 0xffff) + w1 * bf2f(B1.w & 0xffff);
        acc[7] += w0 * bf2f(B0.w >> 16)    + w1 * bf2f(B1.w >> 16);
    }
#pragma unroll
    for (int m = 8; m <= 32; m <<= 1) {
#pragma unroll
        for (int k = 0; k < 8; ++k) acc[k] += __shfl_xor(acc[k], m, 64);
    }
    if (lane < 8) {
        const uint4 S = *(const uint4*)&hb2[(size_t)node * DIM + q * 8];
        float r[8];
        r[0] = dv * (acc[0] + dv * bf2f(S.x & 0xffff) + bias[q * 8 + 0]);
        r[1] = dv * (acc[1] + dv * bf2f(S.x >> 16)    + bias[q * 8 + 1]);
        r[2] = dv * (acc[2] + dv * bf2f(S.y & 0xffff) + bias[q * 8 + 2]);
        r[3] = dv * (acc[3] + dv * bf2f(S.y >> 16)    + bias[q * 8 + 3]);
        r[4] = dv * (acc[4] + dv * bf2f(S.z & 0xffff) + bias[q * 8 + 4]);
        r[5] = dv * (acc[5] + dv * bf2f(S.z >> 16)    + bias[q * 8 + 5]);
        r[6] = dv * (acc[6] + dv * bf2f(S.w & 0xffff) + bias[q * 8 + 6]);
        r[7] = dv * (acc[7] + dv * bf2f(S.w >> 16)    + bias[q * 8 + 7]);
        uint4 o;
        o.x = f2bf(r[0]) | (f2bf(r[1]) << 16);
        o.y = f2bf(r[2]) | (f2bf(r[3]) << 16);
        o.z = f2bf(r[4]) | (f2bf(r[5]) << 16);
        o.w = f2bf(r[6]) | (f2bf(r[7]) << 16);
        *(uint4*)&ob[(size_t)node * DIM + q * 8] = o;
    }
}

// ---------------- fused: layer-2 aggregate + pool + W2 GEMM (flat range) ----

__global__ __launch_bounds__(512) void agg2_pool_gemm(const int* __restrict__ rowptr,
                                                      const u32* __restrict__ csr,
                                                      const u16* __restrict__ hb,
                                                      const float* __restrict__ dinv,
                                                      const float* __restrict__ W2,
                                                      const float* __restrict__ b2,
                                                      float* __restrict__ out) {
    __shared__ float Ws[DIM * DIM];
    __shared__ float wacc[8][DIM];
    __shared__ float pooled[DIM];
    const int t = threadIdx.x;
    const int m = blockIdx.x;

    for (int i = t; i < DIM * DIM; i += 512) Ws[i] = W2[i];

    const int wave = t >> 6;
    const int lane = t & 63;
    const int g = lane >> 3;
    const int q = lane & 7;

    const int start = rowptr[m * 64];
    const int end = rowptr[m * 64 + 64];

    float acc[8];
#pragma unroll
    for (int k = 0; k < 8; ++k) acc[k] = 0.f;

    for (int i = start + wave * 32; i < end; i += 256) {
        const int i0 = i + g;
        const int i1 = i + 8 + g;
        const int i2 = i + 16 + g;
        const int i3 = i + 24 + g;
        const u32 v0 = (i0 < end) ? csr[i0] : 0;
        const u32 v1 = (i1 < end) ? csr[i1] : 0;
        const u32 v2 = (i2 < end) ? csr[i2] : 0;
        const u32 v3 = (i3 < end) ? csr[i3] : 0;
        const float w0 = bf2f(v0 >> 16);
        const float w1 = bf2f(v1 >> 16);
        const float w2 = bf2f(v2 >> 16);
        const float w3 = bf2f(v3 >> 16);
        const uint4 B0 = *(const uint4*)&hb[(size_t)(v0 & 0xffffu) * DIM + q * 8];
        const uint4 B1 = *(const uint4*)&hb[(size_t)(v1 & 0xffffu) * DIM + q * 8];
        const uint4 B2 = *(const uint4*)&hb[(size_t)(v2 & 0xffffu) * DIM + q * 8];
        const uint4 B3 = *(const uint4*)&hb[(size_t)(v3 & 0xffffu) * DIM + q * 8];
        acc[0] += w0 * bf2f(B0.x & 0xffff) + w1 * bf2f(B1.x & 0xffff)
                + w2 * bf2f(B2.x & 0xffff) + w3 * bf2f(B3.x & 0xffff);
        acc[1] += w0 * bf2f(B0.x >> 16)    + w1 * bf2f(B1.x >> 16)
                + w2 * bf2f(B2.x >> 16)    + w3 * bf2f(B3.x >> 16);
        acc[2] += w0 * bf2f(B0.y & 0xffff) + w1 * bf2f(B1.y & 0xffff)
                + w2 * bf2f(B2.y & 0xffff) + w3 * bf2f(B3.y & 0xffff);
        acc[3] += w0 * bf2f(B0.y >> 16)    + w1 * bf2f(B1.y >> 16)
                + w2 * bf2f(B2.y >> 16)    + w3 * bf2f(B3.y >> 16);
        acc[4] += w0 * bf2f(B0.z & 0xffff) + w1 * bf2f(B1.z & 0xffff)
                + w2 * bf2f(B2.z & 0xffff) + w3 * bf2f(B3.z & 0xffff);
        acc[5] += w0 * bf2f(B0.z >> 16)    + w1 * bf2f(B1.z >> 16)
                + w2 * bf2f(B2.z >> 16)    + w3 * bf2f(B3.z >> 16);
        acc[6] += w0 * bf2f(B0.w & 0xffff) + w1 * bf2f(B1.w & 0xffff)
                + w2 * bf2f(B2.w & 0xffff) + w3 * bf2f(B3.w & 0xffff);
        acc[7] += w0 * bf2f(B0.w >> 16)    + w1 * bf2f(B1.w >> 16)
                + w2 * bf2f(B2.w >> 16)    + w3 * bf2f(B3.w >> 16);
    }

    // self terms: wave handles nodes m*64 + wave*8 + g (each exactly once)
    {
        const int node = m * 64 + wave * 8 + g;
        const float dv = dinv[node];
        const uint4 S = *(const uint4*)&hb[(size_t)node * DIM + q * 8];
        acc[0] += dv * bf2f(S.x & 0xffff);
        acc[1] += dv * bf2f(S.x >> 16);
        acc[2] += dv * bf2f(S.y & 0xffff);
        acc[3] += dv * bf2f(S.y >> 16);
        acc[4] += dv * bf2f(S.z & 0xffff);
        acc[5] += dv * bf2f(S.z >> 16);
        acc[6] += dv * bf2f(S.w & 0xffff);
        acc[7] += dv * bf2f(S.w >> 16);
    }

#pragma unroll
    for (int mm = 8; mm <= 32; mm <<= 1) {
#pragma unroll
        for (int k = 0; k < 8; ++k) acc[k] += __shfl_xor(acc[k], mm, 64);
    }
    if (lane < 8) {
#pragma unroll
        for (int k = 0; k < 8; ++k) wacc[wave][q * 8 + k] = acc[k];
    }
    __syncthreads();
    if (t < DIM) {
        float p = 0.f;
#pragma unroll
        for (int w = 0; w < 8; ++w) p += wacc[w][t];
        pooled[t] = p * (1.0f / DIM);
    }
    __syncthreads();
    if (t < DIM) {
        float o = b2[t];
#pragma unroll
        for (int k = 0; k < DIM; ++k) o += pooled[k] * Ws[k * DIM + t];
        out[(size_t)t * M_POOL + m] = o;
    }
}

// ---------------- launcher --------------------------------------------------

extern "C" void kernel_launch(void* const* d_in, const int* in_sizes, int n_in,
                              void* d_out, int out_size, void* d_ws, size_t ws_size,
                              hipStream_t stream) {
    const float* x  = (const float*)d_in[0];
    const int*   ei = (const int*)d_in[1];   // [2][E]
    const float* ew = (const float*)d_in[2];
    const float* W1 = (const float*)d_in[3];
    const float* b1 = (const float*)d_in[4];
    const float* W2 = (const float*)d_in[5];
    const float* b2 = (const float*)d_in[6];
    float* out = (float*)d_out;

    char* w = (char*)d_ws;
    int*   cursor = (int*)w;   w += 1024;
    int*   rowptr = (int*)w;   w += (size_t)(N_NODES + 16) * 4;      // 0.25 MB
    float* dinv   = (float*)w; w += (size_t)N_NODES * 4;             // 0.25 MB
    int2*  csrt   = (int2*)w;  w += (size_t)NCOARSE * SEGCAP * 8;    // 10.5 MB
    u32*   csr    = (u32*)w;   w += (size_t)N_EDGES * 4;             // 4 MB
    u16*   hbf    = (u16*)w;   w += (size_t)N_NODES * DIM * 2;       // 8 MB
    u16*   h1bf   = (u16*)w;                                         // 8 MB

    const int* row = ei;             // edge_index[0]
    const int* col = ei + N_EDGES;   // edge_index[1]

    // build: gemm || coarse-multisplit in one grid, then fine sort (+scan inlined)
    zero_cursor<<<1, 256, 0, stream>>>(cursor);
    fused_gemm_p3<<<FUSED_BLOCKS, 1024, 0, stream>>>(x, W1, hbf, col, row, ew,
                                                     cursor, csrt);
    p4_fine<<<NCOARSE, 512, 0, stream>>>(cursor, csrt, csr, rowptr, dinv, hbf);

    // layer 1 aggregate: h1p = bf16(dv * (A h + b1))   (premultiplied)
    aggregate_l1<<<N_NODES / 4, 256, 0, stream>>>(rowptr, csr, hbf, dinv, b1, h1bf);

    // layer 2 + pool + W2-GEMM fused per window (flat contiguous edge range)
    agg2_pool_gemm<<<M_POOL, 512, 0, stream>>>(rowptr, csr, h1bf, dinv, W2, b2, out);
}